// Round 12
// baseline (302.806 us; speedup 1.0000x reference)
//
#include <hip/hip_runtime.h>

#define NROW 16384
#define ROWI 10246
#define POUT_F (3*33*16384)       // slices: 0=G, 1=D, 2=A
#define NSLOT 324                 // 0..319 tiles; 320=D@t0, 321=D@t2, 322=A@t68, 323=A@t70
#define BF_U16 ((size_t)NSLOT*128*8)
#define PTAB_ROWS 3438
#define PTAB_F (PTAB_ROWS*64)

typedef unsigned int u32;
typedef unsigned long long u64;
typedef unsigned short u16;
typedef short short8 __attribute__((ext_vector_type(8)));
typedef float f32x4 __attribute__((ext_vector_type(4)));

union AFrag { u32 u[4]; short8 s; };
union BFrag { uint4 v; short8 s; };

// Permuted column map induced by the int2-ballot pack:
// tile t, element k (0..31): col = 128*(t>>2) + 64*(t&1) + 2*k + ((t>>1)&1)
__host__ __device__ inline int colof(int t, int k) {
  return 128*(t >> 2) + 64*(t & 1) + 2*k + ((t >> 1) & 1);
}

// ---------------- prep: B fragment table (bf16, MFMA layout, permuted cols) --
// Frag id = (slot*2 + f)*64 + lane ; elem e: k = (lane>>4)*8 + e,
// d = f*16 + (lane&15). Value = segment weight of colof(t,k) if col in the
// slot's range, else 0.
__global__ void prep_bf(const float* __restrict__ Wg, const float* __restrict__ Wd,
                        const float* __restrict__ Wa, u16* __restrict__ Bf) {
  int id = blockIdx.x*256 + threadIdx.x;
  if (id >= NSLOT*128) return;
  int lane = id & 63, f = (id >> 6) & 1, slot = id >> 7;
  int t, clo, chi;
  if (slot < 320) {
    t = slot;
    if (t == 0 || t == 2) { clo = 1; chi = 26; }
    else {
      int c0 = colof(t, 0);
      if (c0 < 2212) { clo = 26; chi = 2212; }
      else           { clo = 2212; chi = 10242; }
    }
  } else if (slot == 320) { t = 0;  clo = 26;   chi = 2212;  }
  else if   (slot == 321) { t = 2;  clo = 26;   chi = 2212;  }
  else if   (slot == 322) { t = 68; clo = 2212; chi = 10242; }
  else                    { t = 70; clo = 2212; chi = 10242; }
  int d  = f*16 + (lane & 15);
  int kb = (lane >> 4)*8;
  u16 o[8];
  #pragma unroll
  for (int e = 0; e < 8; ++e) {
    int c = colof(t, kb + e);
    float v = 0.f;
    if (c >= clo && c < chi) {
      if (chi == 26)        v = Wg[d*25   + (c-1)];
      else if (chi == 2212) v = Wd[d*2186 + (c-26)];
      else                  v = Wa[d*8030 + (c-2212)];
    }
    u32 bits = __float_as_uint(v);                    // RNE float->bf16
    o[e] = (u16)((bits + 0x7FFFu + ((bits >> 16) & 1u)) >> 16);
  }
  uint4 w;
  w.x = (u32)o[0] | ((u32)o[1] << 16);
  w.y = (u32)o[2] | ((u32)o[3] << 16);
  w.z = (u32)o[4] | ((u32)o[5] << 16);
  w.w = (u32)o[6] | ((u32)o[7] << 16);
  *(uint4*)&Bf[(size_t)id*8] = w;
}

// ---------------- prep: folded index-embedding table ----------------
__global__ void prep_p(const float* __restrict__ er, const float* __restrict__ eg,
                       const float* __restrict__ ea, const float* __restrict__ eo,
                       const float* __restrict__ ez, const float* __restrict__ W1,
                       float* __restrict__ P) {
  int id = blockIdx.x*256 + threadIdx.x;
  if (id >= PTAB_F) return;
  int r = id >> 6, o = id & 63;
  const float* emb; int woff;
  if (r < 6)       { emb = er + r*32;       woff = 0;   }
  else if (r < 8)  { emb = eg + (r-6)*32;   woff = 128; }
  else if (r < 15) { emb = ea + (r-8)*32;   woff = 160; }
  else if (r < 36) { emb = eo + (r-15)*32;  woff = 192; }
  else             { emb = ez + (r-36)*32;  woff = 224; }
  const float* w = W1 + o*256 + woff;
  float s = 0.f;
  #pragma unroll
  for (int c2 = 0; c2 < 32; ++c2) s += emb[c2]*w[c2];
  P[id] = s;
}

__global__ void prep_w2t(const float* __restrict__ W2, float* __restrict__ W2t) {
  int id = blockIdx.x*256 + threadIdx.x;
  if (id >= 64*64) return;
  int o = id >> 6, o2 = id & 63;
  W2t[o*64 + o2] = W2[o2*64 + o];
}

// ---------------- fused pack + MFMA + combine kernel ----------------
// Block = 512 thr (8 waves) = 32 rows. Phase 1: int2 linear stream -> ballot ->
// LDS bit matrix (permuted layout). Phase 2: wave (s=wv&1 rowset, q=wv>>1
// K-quarter of 80 tiles) MFMA. Phase 3: merge in (aliased) LDS, write pout.
__global__ __launch_bounds__(512, 4) void fusedK(
    const int* __restrict__ x, const u16* __restrict__ Bf,
    float* __restrict__ pout, int* __restrict__ side) {
  __shared__ __align__(16) u32 smem[32*324];   // 41472 B; aliased as poutL later

  const int lane = threadIdx.x & 63;
  const int wv   = threadIdx.x >> 6;           // 0..7
  const int row0 = blockIdx.x * 32;
  const int r = lane & 15, g = lane >> 4, g8 = g*8;

  // ---- phase 1: wave packs rows wv*4..wv*4+3; 80 int2-chunks of 128 cols ----
#define LDB(V, BB) do { _Pragma("unroll")                                      \
    for (int k_ = 0; k_ < 16; ++k_) V[k_] = base2[((BB)*16 + k_)*64 + lane]; } while (0)
#define PRC(V, BB) do { u32 keep = 0;                                          \
    _Pragma("unroll")                                                          \
    for (int k_ = 0; k_ < 16; ++k_) {                                          \
      const u64 b0 = __ballot(V[k_].x != 0);                                   \
      const u64 b1 = __ballot(V[k_].y != 0);                                   \
      keep = (lane == k_*4)     ? (u32)b0        : keep;                       \
      keep = (lane == k_*4 + 1) ? (u32)(b0>>32)  : keep;                       \
      keep = (lane == k_*4 + 2) ? (u32)b1        : keep;                       \
      keep = (lane == k_*4 + 3) ? (u32)(b1>>32)  : keep;                       \
    }                                                                          \
    orow[(BB)*64 + lane] = keep; } while (0)

  for (int ir = 0; ir < 4; ++ir) {
    const int rL = wv*4 + ir;
    const int2* base2 = (const int2*)(x + (size_t)(row0 + rL)*ROWI);
    u32* orow = &smem[rL*324];
    int2 va[16], vb[16];
    LDB(va, 0);
    LDB(vb, 1); PRC(va, 0);
    LDB(va, 2); PRC(vb, 1);
    LDB(vb, 3); PRC(va, 2);
    LDB(va, 4); PRC(vb, 3);
    PRC(va, 4);
  }
#undef LDB
#undef PRC
  {
    const int i2 = lane >> 3, j = lane & 7;
    if (lane < 32 && j < 7) {
      const int* bp = x + (size_t)(row0 + wv*4 + i2)*ROWI;
      side[(row0 + wv*4 + i2)*8 + j] = (j == 0) ? bp[0] : bp[10239 + j];
    }
  }
  __syncthreads();

  // ---- phase 2 ----
  const int s16 = (wv & 1) * 16;
  const int qq  = wv >> 1;                     // K quarter
  const int tb  = qq * 80;
  const int tmax = tb + 79;
  const u32* brow = &smem[(s16 + r)*324];
  const uint4* pB = (const uint4*)Bf + lane;   // + (t*2+f)*64

  f32x4 z = {0.f,0.f,0.f,0.f};
  f32x4 G0=z,G1=z,D0=z,D1=z,A0=z,A1=z;
  int cG=0,cD=0,cA=0;

  uint4 B00 = pB[((tb+0)*2)*64], B01 = pB[((tb+0)*2+1)*64];
  uint4 B10 = pB[((tb+1)*2)*64], B11 = pB[((tb+1)*2+1)*64];
  uint4 B20 = pB[((tb+2)*2)*64], B21 = pB[((tb+2)*2+1)*64];
  uint4 B30 = pB[((tb+3)*2)*64], B31 = pB[((tb+3)*2+1)*64];

#define MFMA_(AF, B, ACC) __builtin_amdgcn_mfma_f32_16x16x32_bf16((AF).s, (B).s, ACC, 0,0,0)
#define AFB(AF, BY)                                                            \
    AF.u[0] = __umul24(((BY)      & 1u) + ((((BY) >> 1) & 1u) << 16), 0x3F80u);\
    AF.u[1] = __umul24((((BY)>>2) & 1u) + ((((BY) >> 3) & 1u) << 16), 0x3F80u);\
    AF.u[2] = __umul24((((BY)>>4) & 1u) + ((((BY) >> 5) & 1u) << 16), 0x3F80u);\
    AF.u[3] = __umul24((((BY)>>6) & 1u) + ((((BY) >> 7) & 1u) << 16), 0x3F80u);

#define TPURE(SEG, WORD, BR, TT) do {                                          \
    const u32 by_ = ((WORD) >> g8) & 0xFFu;                                    \
    AFrag af_; AFB(af_, by_);                                                  \
    BFrag b0_, b1_; b0_.v = BR##0; b1_.v = BR##1;                              \
    SEG##0 = MFMA_(af_, b0_, SEG##0); SEG##1 = MFMA_(af_, b1_, SEG##1);        \
    c##SEG += __popc(by_);                                                     \
    int tn_ = (TT) + 4; if (tn_ > tmax) tn_ = tmax;                            \
    BR##0 = pB[(tn_*2)*64]; BR##1 = pB[(tn_*2+1)*64]; } while (0)

#define TMIXED(PRI, SEC, WORD, BR, SLOT, MPRI, MSEC, TT) do {                  \
    const u32 by_ = ((WORD) >> g8) & 0xFFu;                                    \
    AFrag af_; AFB(af_, by_);                                                  \
    BFrag b0_, b1_, e0_, e1_; b0_.v = BR##0; b1_.v = BR##1;                    \
    e0_.v = pB[((SLOT)*2)*64]; e1_.v = pB[((SLOT)*2+1)*64];                    \
    PRI##0 = MFMA_(af_, b0_, PRI##0); PRI##1 = MFMA_(af_, b1_, PRI##1);        \
    SEC##0 = MFMA_(af_, e0_, SEC##0); SEC##1 = MFMA_(af_, e1_, SEC##1);        \
    c##PRI += __popc(by_ & (((MPRI) >> g8) & 0xFFu));                          \
    c##SEC += __popc(by_ & (((MSEC) >> g8) & 0xFFu));                          \
    int tn_ = (TT) + 4; if (tn_ > tmax) tn_ = tmax;                            \
    BR##0 = pB[(tn_*2)*64]; BR##1 = pB[(tn_*2+1)*64]; } while (0)

  if (qq == 0) {
    for (int i = 0; i < 20; ++i) {
      const int t0 = 4*i;
      const uint4 W4 = *(const uint4*)&brow[t0];
      if (i == 0) {
        // tiles 0,2: G-primary (bits: G=1..12 / 0..12), D in bits 13..31 (extras 320/321)
        TMIXED(G, D, W4.x, B0, 320, 0x00001FFEu, 0xFFFFE000u, 0);
        TPURE (D,    W4.y, B1, 1);
        TMIXED(G, D, W4.z, B2, 321, 0x00001FFFu, 0xFFFFE000u, 2);
        TPURE (D,    W4.w, B3, 3);
      } else if (i == 17) {
        // tiles 68,70: D bits 0..17, A bits 18..31 (extras 322/323)
        TMIXED(D, A, W4.x, B0, 322, 0x0003FFFFu, 0xFFFC0000u, 68);
        TPURE (A,    W4.y, B1, 69);
        TMIXED(D, A, W4.z, B2, 323, 0x0003FFFFu, 0xFFFC0000u, 70);
        TPURE (A,    W4.w, B3, 71);
      } else if (i < 17) {
        TPURE(D, W4.x, B0, t0);   TPURE(D, W4.y, B1, t0+1);
        TPURE(D, W4.z, B2, t0+2); TPURE(D, W4.w, B3, t0+3);
      } else {
        TPURE(A, W4.x, B0, t0);   TPURE(A, W4.y, B1, t0+1);
        TPURE(A, W4.z, B2, t0+2); TPURE(A, W4.w, B3, t0+3);
      }
    }
  } else {
    for (int i = 0; i < 20; ++i) {
      const int t0 = tb + 4*i;
      const uint4 W4 = *(const uint4*)&brow[t0];
      TPURE(A, W4.x, B0, t0);   TPURE(A, W4.y, B1, t0+1);
      TPURE(A, W4.z, B2, t0+2); TPURE(A, W4.w, B3, t0+3);
    }
  }
#undef TPURE
#undef TMIXED

  cG += __shfl_xor(cG,16); cG += __shfl_xor(cG,32);
  cD += __shfl_xor(cD,16); cD += __shfl_xor(cD,32);
  cA += __shfl_xor(cA,16); cA += __shfl_xor(cA,32);

  __syncthreads();                 // all bit reads done; safe to alias smem
  float* poutL = (float*)smem;     // [6][33][32]: 0=G,1=D,2=A(q0),3..5=A(q1..3)

#define STOF(P, SLOT) do {                                                     \
    *(f32x4*)&poutL[((SLOT)*33 + r)*32      + s16 + 4*g] = P##0;               \
    *(f32x4*)&poutL[((SLOT)*33 + 16 + r)*32 + s16 + 4*g] = P##1; } while (0)

  if (qq == 0) {
    STOF(G, 0); STOF(D, 1); STOF(A, 2);
    if (lane < 16) {
      poutL[(0*33 + 32)*32 + s16 + lane] = (float)cG;
      poutL[(1*33 + 32)*32 + s16 + lane] = (float)cD;
      poutL[(2*33 + 32)*32 + s16 + lane] = (float)cA;
    }
  } else {
    STOF(A, 2 + qq);
    if (lane < 16) poutL[((2+qq)*33 + 32)*32 + s16 + lane] = (float)cA;
  }
#undef STOF
  __syncthreads();

  // ---- phase 3: merge A-quarters, write global pout ----
  for (int id = threadIdx.x; id < 3*33*32; id += 512) {
    const int seg = id / (33*32);
    const int rem = id - seg*(33*32);
    const int d = rem >> 5, row = rem & 31;
    float v = poutL[(seg*33 + d)*32 + row];
    if (seg == 2)
      v += poutL[(3*33 + d)*32 + row] + poutL[(4*33 + d)*32 + row]
         + poutL[(5*33 + d)*32 + row];
    pout[((size_t)seg*33 + d)*16384 + row0 + row] = v;
  }
}

// ---------------- reduce + tail + MLP kernel ----------------
__global__ __launch_bounds__(64, 1) void k2(
    const int* __restrict__ side, const float* __restrict__ pout,
    const float* __restrict__ Wa, const float* __restrict__ P,
    const float* __restrict__ W1, const float* __restrict__ b1,
    const float* __restrict__ W2t, const float* __restrict__ b2,
    const float* __restrict__ Wout, const float* __restrict__ bout,
    float* __restrict__ out) {
  const int row = blockIdx.x*64 + threadIdx.x;
  const int4 s0 = *(const int4*)&side[row*8];      // rate, x10240, x10241, gender
  const int4 s1 = *(const int4*)&side[row*8 + 4];  // age, occ, area, (pad)

#define PSL(SL, D) pout[(size_t)((SL)*33 + (D))*16384 + row]
  float mG[32], mD[32], mA[32];
  #pragma unroll
  for (int d = 0; d < 32; ++d) {
    mG[d] = PSL(0, d);
    mD[d] = PSL(1, d);
    mA[d] = PSL(2, d);
  }
  float cG = PSL(0, 32);
  float cD = PSL(1, 32);
  float cA = PSL(2, 32);
#undef PSL

  // tail actor columns 10240, 10241 (= Wa cols 8028, 8029)
  {
    const float t0 = (float)s0.y, t1 = (float)s0.z;
    cA += t0 + t1;
    #pragma unroll
    for (int d = 0; d < 32; ++d)
      mA[d] = fmaf(t1, Wa[d*8030 + 8029], fmaf(t0, Wa[d*8030 + 8028], mA[d]));
  }

  #pragma unroll
  for (int d = 0; d < 32; ++d) { mG[d] /= cG; mD[d] /= cD; mA[d] /= cA; }

  const int ridx = s0.x;
  const int gi = s0.w, ai = s1.x, oi = s1.y, ari = s1.z;
  const float* Pr = P + (size_t)ridx*64;
  const float* Pg = P + (size_t)(6 + gi)*64;
  const float* Pa = P + (size_t)(8 + ai)*64;
  const float* Po = P + (size_t)(15 + oi)*64;
  const float* Pz = P + (size_t)(36 + ari)*64;

  float h1[64];
  #pragma unroll
  for (int o = 0; o < 64; ++o)
    h1[o] = b1[o] + ((Pr[o] + Pg[o]) + (Pa[o] + Po[o])) + Pz[o];

  #pragma unroll
  for (int o = 0; o < 64; ++o) {
    const float* w = W1 + o*256;
    float a = h1[o];
    #pragma unroll
    for (int d = 0; d < 32; ++d) a = fmaf(mG[d], w[32+d], a);
    #pragma unroll
    for (int d = 0; d < 32; ++d) a = fmaf(mD[d], w[64+d], a);
    #pragma unroll
    for (int d = 0; d < 32; ++d) a = fmaf(mA[d], w[96+d], a);
    h1[o] = fmaxf(a, 0.f);
  }

  float h2[64];
  #pragma unroll
  for (int o2 = 0; o2 < 64; ++o2) h2[o2] = b2[o2];
  #pragma unroll
  for (int o = 0; o < 64; ++o) {
    const float h = h1[o];
    const float* wr = W2t + o*64;
    #pragma unroll
    for (int o2 = 0; o2 < 64; ++o2) h2[o2] = fmaf(h, wr[o2], h2[o2]);
  }
  float acc = bout[0];
  #pragma unroll
  for (int o2 = 0; o2 < 64; ++o2) acc = fmaf(fmaxf(h2[o2], 0.f), Wout[o2], acc);
  out[row] = acc;
}

// ---------------- launcher ----------------
extern "C" void kernel_launch(void* const* d_in, const int* in_sizes, int n_in,
                              void* d_out, int out_size, void* d_ws, size_t ws_size,
                              hipStream_t stream) {
  (void)in_sizes; (void)n_in; (void)out_size; (void)ws_size;
  const int*   x        = (const int*)  d_in[0];
  const float* emb_rate = (const float*)d_in[1];
  const float* W_genre  = (const float*)d_in[2];
  const float* W_dir    = (const float*)d_in[3];
  const float* W_actor  = (const float*)d_in[4];
  const float* emb_gen  = (const float*)d_in[5];
  const float* emb_age  = (const float*)d_in[6];
  const float* emb_occ  = (const float*)d_in[7];
  const float* emb_area = (const float*)d_in[8];
  const float* W1   = (const float*)d_in[9];
  const float* b1   = (const float*)d_in[10];
  const float* W2   = (const float*)d_in[11];
  const float* b2   = (const float*)d_in[12];
  const float* Wout = (const float*)d_in[13];
  const float* bout = (const float*)d_in[14];
  float* outp = (float*)d_out;

  float* ws   = (float*)d_ws;
  float* pout = ws;                                   // 3*33*16384 floats
  u16*   Bf   = (u16*)(ws + POUT_F);                  // 648 KB, 16B-aligned
  float* P    = (float*)(Bf + BF_U16);
  float* W2t  = P + PTAB_F;
  int*   side = (int*)(W2t + 64*64);                  // 16384*8 ints

  prep_bf<<<(NSLOT*128 + 255)/256, 256, 0, stream>>>(W_genre, W_dir, W_actor, Bf);
  prep_p<<<(PTAB_F + 255)/256, 256, 0, stream>>>(emb_rate, emb_gen, emb_age, emb_occ,
                                                 emb_area, W1, P);
  prep_w2t<<<16, 256, 0, stream>>>(W2, W2t);

  fusedK<<<NROW/32, 512, 0, stream>>>(x, Bf, pout, side);

  k2<<<NROW/64, 64, 0, stream>>>(side, pout, W_actor, P, W1, b1, W2t, b2, Wout, bout, outp);
}

// Round 13
// 300.629 us; speedup vs baseline: 1.0072x; 1.0072x over previous
//
#include <hip/hip_runtime.h>

#define NROW 16384
#define ROWI 10246
#define POUT_F (3*33*16384)       // slices: 0=G, 1=D, 2=A
#define NSLOT 328                 // 0..319 tiles; 320..323 D-extra@{0,2,4,6}; 324..327 A-extra@{65,67,69,71}
#define BF_U16 ((size_t)2*NSLOT*128*8)
#define PTAB_ROWS 3438
#define PTAB_F (PTAB_ROWS*64)

typedef unsigned int u32;
typedef unsigned long long u64;
typedef unsigned short u16;
typedef short short8 __attribute__((ext_vector_type(8)));
typedef float f32x4 __attribute__((ext_vector_type(4)));

union AFrag { u32 u[4]; short8 s; };
union BFrag { uint4 v; short8 s; };

// Column map induced by int4-ballot pack at window base 2p:
// tile t (=word), k bit: col = 2p + 256*(t>>3) + 128*(t&1) + 4k + ((t>>1)&3)
__host__ __device__ inline int colof4(int t, int k, int p) {
  return 2*p + 256*(t >> 3) + 128*(t & 1) + 4*k + ((t >> 1) & 3);
}

// ---------------- prep: B fragment table (bf16, MFMA layout, per parity) ----
__global__ void prep_bf(const float* __restrict__ Wg, const float* __restrict__ Wd,
                        const float* __restrict__ Wa, u16* __restrict__ Bf) {
  int id = blockIdx.x*256 + threadIdx.x;
  if (id >= 2*NSLOT*128) return;
  int lane = id & 63, f = (id >> 6) & 1, slot = (id >> 7) % NSLOT, p = id / (NSLOT*128);
  int t, seg;                                   // seg: 0=G,1=D,2=A
  if (slot < 320) {
    t = slot;
    seg = (t==0||t==2||t==4||t==6) ? 0 : (t < 72 ? 1 : 2);
  } else if (slot < 324) { t = 2*(slot - 320);      seg = 1; }
  else                   { t = 65 + 2*(slot - 324); seg = 2; }
  int d  = f*16 + (lane & 15);
  int kb = (lane >> 4)*8;
  u16 o[8];
  #pragma unroll
  for (int e = 0; e < 8; ++e) {
    int c = colof4(t, kb + e, p);
    float v = 0.f;
    if (seg == 0)      { if (c >= 1    && c < 26)    v = Wg[d*25   + (c-1)];    }
    else if (seg == 1) { if (c >= 26   && c < 2212)  v = Wd[d*2186 + (c-26)];   }
    else               { if (c >= 2212 && c < 10242) v = Wa[d*8030 + (c-2212)]; }
    u32 bits = __float_as_uint(v);              // RNE float->bf16
    o[e] = (u16)((bits + 0x7FFFu + ((bits >> 16) & 1u)) >> 16);
  }
  uint4 w;
  w.x = (u32)o[0] | ((u32)o[1] << 16);
  w.y = (u32)o[2] | ((u32)o[3] << 16);
  w.z = (u32)o[4] | ((u32)o[5] << 16);
  w.w = (u32)o[6] | ((u32)o[7] << 16);
  *(uint4*)&Bf[(size_t)id*8] = w;
}

// ---------------- prep: folded index-embedding table ----------------
__global__ void prep_p(const float* __restrict__ er, const float* __restrict__ eg,
                       const float* __restrict__ ea, const float* __restrict__ eo,
                       const float* __restrict__ ez, const float* __restrict__ W1,
                       float* __restrict__ P) {
  int id = blockIdx.x*256 + threadIdx.x;
  if (id >= PTAB_F) return;
  int r = id >> 6, o = id & 63;
  const float* emb; int woff;
  if (r < 6)       { emb = er + r*32;       woff = 0;   }
  else if (r < 8)  { emb = eg + (r-6)*32;   woff = 128; }
  else if (r < 15) { emb = ea + (r-8)*32;   woff = 160; }
  else if (r < 36) { emb = eo + (r-15)*32;  woff = 192; }
  else             { emb = ez + (r-36)*32;  woff = 224; }
  const float* w = W1 + o*256 + woff;
  float s = 0.f;
  #pragma unroll
  for (int c2 = 0; c2 < 32; ++c2) s += emb[c2]*w[c2];
  P[id] = s;
}

__global__ void prep_w2t(const float* __restrict__ W2, float* __restrict__ W2t) {
  int id = blockIdx.x*256 + threadIdx.x;
  if (id >= 64*64) return;
  int o = id >> 6, o2 = id & 63;
  W2t[o*64 + o2] = W2[o2*64 + o];
}

// ---------------- fused pack(int4) + MFMA + combine ----------------
// Block = 256 thr (4 waves) = 32 rows. Phase 1: each wave packs 8 rows via
// 16B/lane int4 loads + ballot (parity window base 2p). Phase 2: wave =
// (parity p = wv&1, K-half hh = wv>>1); rows {2r+p}, tiles [160hh,160hh+160).
// Phase 3: merge halves in aliased LDS, write pout[3][33][16384].
__global__ __launch_bounds__(256, 2) void fusedK(
    const int* __restrict__ x, const u16* __restrict__ Bf,
    float* __restrict__ pout, int* __restrict__ side) {
  __shared__ __align__(16) u32 smem[32*324];    // 41.5 KB; stride 324 (16B mult)

  const int lane = threadIdx.x & 63;
  const int wv   = threadIdx.x >> 6;
  const int row0 = blockIdx.x * 32;
  const int r = lane & 15, g = lane >> 4, g8 = g*8;

  // ---- phase 1 ----
#define LD1(V, GB) do { _Pragma("unroll")                                      \
    for (int k_ = 0; k_ < 8; ++k_) V[k_] = b4[((GB)*8 + k_)*64 + lane]; } while (0)
#define ST1(V, GB) do { u32 keep = 0;                                          \
    _Pragma("unroll")                                                          \
    for (int ii = 0; ii < 8; ++ii) {                                           \
      u64 b;                                                                   \
      b = __ballot(V[ii].x != 0);                                              \
      keep = (lane == ii*8+0) ? (u32)b : keep;                                 \
      keep = (lane == ii*8+1) ? (u32)(b>>32) : keep;                           \
      b = __ballot(V[ii].y != 0);                                              \
      keep = (lane == ii*8+2) ? (u32)b : keep;                                 \
      keep = (lane == ii*8+3) ? (u32)(b>>32) : keep;                           \
      b = __ballot(V[ii].z != 0);                                              \
      keep = (lane == ii*8+4) ? (u32)b : keep;                                 \
      keep = (lane == ii*8+5) ? (u32)(b>>32) : keep;                           \
      b = __ballot(V[ii].w != 0);                                              \
      keep = (lane == ii*8+6) ? (u32)b : keep;                                 \
      keep = (lane == ii*8+7) ? (u32)(b>>32) : keep;                           \
    }                                                                          \
    orow[(GB)*64 + lane] = keep; } while (0)

  for (int ir = 0; ir < 8; ++ir) {
    const int lr = wv*8 + ir;
    const int pp = lr & 1;
    const int4* b4 = (const int4*)(x + (size_t)(row0 + lr)*ROWI + 2*pp);
    u32* orow = &smem[lr*324];
    int4 va[8], vb[8];
    LD1(va, 0);
    LD1(vb, 1); ST1(va, 0);
    LD1(va, 2); ST1(vb, 1);
    LD1(vb, 3); ST1(va, 2);
    LD1(va, 4); ST1(vb, 3);
    ST1(va, 4);
  }
#undef LD1
#undef ST1
  {
    const int rr = lane >> 3, j = lane & 7;     // 8 rows x 8 side cols per wave
    const int* xr = x + (size_t)(row0 + wv*8 + rr)*ROWI;
    side[(row0 + wv*8 + rr)*8 + j] = (j < 2) ? xr[j] : xr[10238 + j];
  }
  __syncthreads();

  // ---- phase 2 ----
  const int p  = wv & 1;
  const int hh = wv >> 1;
  const int tb = hh*160, tmax = tb + 159;
  const u32* brow = &smem[(2*r + p)*324];
  const uint4* pB = (const uint4*)Bf + (size_t)p*NSLOT*2*64 + lane;  // +(slot*2+f)*64

  f32x4 z = {0.f,0.f,0.f,0.f};
  f32x4 G0=z,G1=z,D0=z,D1=z,A0=z,A1=z;
  int cG=0,cD=0,cA=0;

  uint4 B00 = pB[((tb+0)*2)*64], B01 = pB[((tb+0)*2+1)*64];
  uint4 B10 = pB[((tb+1)*2)*64], B11 = pB[((tb+1)*2+1)*64];
  uint4 B20 = pB[((tb+2)*2)*64], B21 = pB[((tb+2)*2+1)*64];
  uint4 B30 = pB[((tb+3)*2)*64], B31 = pB[((tb+3)*2+1)*64];

#define MFMA_(AF, B, ACC) __builtin_amdgcn_mfma_f32_16x16x32_bf16((AF).s, (B).s, ACC, 0,0,0)
#define AFB(AF, BY)                                                            \
    AF.u[0] = __umul24(((BY)      & 1u) + ((((BY) >> 1) & 1u) << 16), 0x3F80u);\
    AF.u[1] = __umul24((((BY)>>2) & 1u) + ((((BY) >> 3) & 1u) << 16), 0x3F80u);\
    AF.u[2] = __umul24((((BY)>>4) & 1u) + ((((BY) >> 5) & 1u) << 16), 0x3F80u);\
    AF.u[3] = __umul24((((BY)>>6) & 1u) + ((((BY) >> 7) & 1u) << 16), 0x3F80u);
#define RELOAD(BR, TT) do { int tn_ = (TT) + 4; if (tn_ > tmax) tn_ = tmax;    \
    BR##0 = pB[(tn_*2)*64]; BR##1 = pB[(tn_*2+1)*64]; } while (0)

#define TPURE(SEG, WORD, BR, TT) do {                                          \
    const u32 by_ = ((WORD) >> g8) & 0xFFu;                                    \
    AFrag af_; AFB(af_, by_);                                                  \
    BFrag b0_, b1_; b0_.v = BR##0; b1_.v = BR##1;                              \
    SEG##0 = MFMA_(af_, b0_, SEG##0); SEG##1 = MFMA_(af_, b1_, SEG##1);        \
    c##SEG += __popc(by_);                                                     \
    RELOAD(BR, TT); } while (0)

#define TMIX(PRI, SEC, WORD, BR, XS, MPRI, MSEC, TT) do {                      \
    const u32 by_ = ((WORD) >> g8) & 0xFFu;                                    \
    AFrag af_; AFB(af_, by_);                                                  \
    BFrag b0_, b1_, e0_, e1_; b0_.v = BR##0; b1_.v = BR##1;                    \
    e0_.v = pB[((XS)*2)*64]; e1_.v = pB[((XS)*2+1)*64];                        \
    PRI##0 = MFMA_(af_, b0_, PRI##0); PRI##1 = MFMA_(af_, b1_, PRI##1);        \
    SEC##0 = MFMA_(af_, e0_, SEC##0); SEC##1 = MFMA_(af_, e1_, SEC##1);        \
    c##PRI += __popc(by_ & (u32)((MPRI) >> g8));                               \
    c##SEC += __popc(by_ & (u32)((MSEC) >> g8));                               \
    RELOAD(BR, TT); } while (0)

  for (int j = 0; j < 40; ++j) {
    const int t0 = tb + 4*j;
    const uint4 W4 = *(const uint4*)&brow[t0];
    if (hh == 0 && j == 0) {
      TMIX(G, D, W4.x, B0, 320, (p ? 0x3Fu : 0x7Eu), (p ? 0xFFFFFFC0u : 0xFFFFFF80u), 0);
      TPURE(D,    W4.y, B1, 1);
      TMIX(G, D, W4.z, B2, 321, (p ? 0x3Fu : 0x7Fu), (p ? 0xFFFFFFC0u : 0xFFFFFF80u), 2);
      TPURE(D,    W4.w, B3, 3);
    } else if (hh == 0 && j == 1) {
      TMIX(G, D, W4.x, B0, 322, 0x3Fu, 0xFFFFFFC0u, 4);
      TPURE(D,    W4.y, B1, 5);
      TMIX(G, D, W4.z, B2, 323, 0x3Fu, 0xFFFFFFC0u, 6);
      TPURE(D,    W4.w, B3, 7);
    } else if (hh == 0 && j == 16) {
      TPURE(D,    W4.x, B0, 64);
      TMIX(D, A, W4.y, B1, 324, 0x1FFu, 0xFFFFFE00u, 65);
      TPURE(D,    W4.z, B2, 66);
      TMIX(D, A, W4.w, B3, 325, 0x1FFu, 0xFFFFFE00u, 67);
    } else if (hh == 0 && j == 17) {
      TPURE(D,    W4.x, B0, 68);
      TMIX(D, A, W4.y, B1, 326, (p ? 0xFFu : 0x1FFu), (p ? 0xFFFFFF00u : 0xFFFFFE00u), 69);
      TPURE(D,    W4.z, B2, 70);
      TMIX(D, A, W4.w, B3, 327, (p ? 0xFFu : 0x1FFu), (p ? 0xFFFFFF00u : 0xFFFFFE00u), 71);
    } else if (hh == 0 && j < 16) {
      TPURE(D, W4.x, B0, t0);   TPURE(D, W4.y, B1, t0+1);
      TPURE(D, W4.z, B2, t0+2); TPURE(D, W4.w, B3, t0+3);
    } else {
      TPURE(A, W4.x, B0, t0);   TPURE(A, W4.y, B1, t0+1);
      TPURE(A, W4.z, B2, t0+2); TPURE(A, W4.w, B3, t0+3);
    }
  }
#undef TPURE
#undef TMIX
#undef RELOAD

  cG += __shfl_xor(cG,16); cG += __shfl_xor(cG,32);
  cD += __shfl_xor(cD,16); cD += __shfl_xor(cD,32);
  cA += __shfl_xor(cA,16); cA += __shfl_xor(cA,32);

  __syncthreads();                  // bits fully consumed; alias smem
  float* poutL = (float*)smem;      // [6][33][32]: (hh*3+seg)
  const int sb = hh*3;

#define STOF(P0_, P1_, SLOT) do { _Pragma("unroll")                            \
    for (int q2 = 0; q2 < 4; ++q2) {                                           \
      const int rl = 2*(4*g + q2) + p;                                         \
      poutL[((SLOT)*33 + r)*32 + rl]      = P0_[q2];                           \
      poutL[((SLOT)*33 + 16 + r)*32 + rl] = P1_[q2];                           \
    } } while (0)
  STOF(G0, G1, sb+0);
  STOF(D0, D1, sb+1);
  STOF(A0, A1, sb+2);
  if (lane < 16) {
    poutL[((sb+0)*33 + 32)*32 + 2*lane + p] = (float)cG;
    poutL[((sb+1)*33 + 32)*32 + 2*lane + p] = (float)cD;
    poutL[((sb+2)*33 + 32)*32 + 2*lane + p] = (float)cA;
  }
#undef STOF
  __syncthreads();

  for (int id = threadIdx.x; id < 3*33*32; id += 256) {
    const int seg = id / (33*32);
    const int rem = id - seg*(33*32);
    const int d = rem >> 5, row = rem & 31;
    const float v = poutL[(seg*33 + d)*32 + row] + poutL[((3+seg)*33 + d)*32 + row];
    pout[((size_t)seg*33 + d)*16384 + row0 + row] = v;
  }
}

// ---------------- reduce + tail + MLP kernel ----------------
__global__ __launch_bounds__(64, 1) void k2(
    const int* __restrict__ side, const float* __restrict__ pout,
    const float* __restrict__ Wg, const float* __restrict__ Wa,
    const float* __restrict__ P, const float* __restrict__ W1,
    const float* __restrict__ b1, const float* __restrict__ W2t,
    const float* __restrict__ b2, const float* __restrict__ Wout,
    const float* __restrict__ bout, float* __restrict__ out) {
  const int row = blockIdx.x*64 + threadIdx.x;
  const int4 s0 = *(const int4*)&side[row*8];      // x0, x1, x10240, x10241
  const int4 s1 = *(const int4*)&side[row*8 + 4];  // gender, age, occ, area

#define PSL(SL, D) pout[(size_t)((SL)*33 + (D))*16384 + row]
  float mG[32], mD[32], mA[32];
  #pragma unroll
  for (int d = 0; d < 32; ++d) {
    mG[d] = PSL(0, d);
    mD[d] = PSL(1, d);
    mA[d] = PSL(2, d);
  }
  float cG = PSL(0, 32);
  float cD = PSL(1, 32);
  float cA = PSL(2, 32);
#undef PSL

  if ((row & 1) == 0) {
    // even rows: window [0,10240) -> add tail actor cols 10240,10241
    const float t0 = (float)s0.z, t1 = (float)s0.w;
    cA += t0 + t1;
    #pragma unroll
    for (int d = 0; d < 32; ++d)
      mA[d] = fmaf(t1, Wa[d*8030 + 8029], fmaf(t0, Wa[d*8030 + 8028], mA[d]));
  } else {
    // odd rows: window [2,10242) -> add genre col 1
    const float x1 = (float)s0.y;
    cG += x1;
    #pragma unroll
    for (int d = 0; d < 32; ++d)
      mG[d] = fmaf(x1, Wg[d*25], mG[d]);
  }

  #pragma unroll
  for (int d = 0; d < 32; ++d) { mG[d] /= cG; mD[d] /= cD; mA[d] /= cA; }

  const int ridx = s0.x;
  const int gi = s1.x, ai = s1.y, oi = s1.z, ari = s1.w;
  const float* Pr = P + (size_t)ridx*64;
  const float* Pg = P + (size_t)(6 + gi)*64;
  const float* Pa = P + (size_t)(8 + ai)*64;
  const float* Po = P + (size_t)(15 + oi)*64;
  const float* Pz = P + (size_t)(36 + ari)*64;

  float h1[64];
  #pragma unroll
  for (int o = 0; o < 64; ++o)
    h1[o] = b1[o] + ((Pr[o] + Pg[o]) + (Pa[o] + Po[o])) + Pz[o];

  #pragma unroll
  for (int o = 0; o < 64; ++o) {
    const float* w = W1 + o*256;
    float a = h1[o];
    #pragma unroll
    for (int d = 0; d < 32; ++d) a = fmaf(mG[d], w[32+d], a);
    #pragma unroll
    for (int d = 0; d < 32; ++d) a = fmaf(mD[d], w[64+d], a);
    #pragma unroll
    for (int d = 0; d < 32; ++d) a = fmaf(mA[d], w[96+d], a);
    h1[o] = fmaxf(a, 0.f);
  }

  float h2[64];
  #pragma unroll
  for (int o2 = 0; o2 < 64; ++o2) h2[o2] = b2[o2];
  #pragma unroll
  for (int o = 0; o < 64; ++o) {
    const float h = h1[o];
    const float* wr = W2t + o*64;
    #pragma unroll
    for (int o2 = 0; o2 < 64; ++o2) h2[o2] = fmaf(h, wr[o2], h2[o2]);
  }
  float acc = bout[0];
  #pragma unroll
  for (int o2 = 0; o2 < 64; ++o2) acc = fmaf(fmaxf(h2[o2], 0.f), Wout[o2], acc);
  out[row] = acc;
}

// ---------------- launcher ----------------
extern "C" void kernel_launch(void* const* d_in, const int* in_sizes, int n_in,
                              void* d_out, int out_size, void* d_ws, size_t ws_size,
                              hipStream_t stream) {
  (void)in_sizes; (void)n_in; (void)out_size; (void)ws_size;
  const int*   x        = (const int*)  d_in[0];
  const float* emb_rate = (const float*)d_in[1];
  const float* W_genre  = (const float*)d_in[2];
  const float* W_dir    = (const float*)d_in[3];
  const float* W_actor  = (const float*)d_in[4];
  const float* emb_gen  = (const float*)d_in[5];
  const float* emb_age  = (const float*)d_in[6];
  const float* emb_occ  = (const float*)d_in[7];
  const float* emb_area = (const float*)d_in[8];
  const float* W1   = (const float*)d_in[9];
  const float* b1   = (const float*)d_in[10];
  const float* W2   = (const float*)d_in[11];
  const float* b2   = (const float*)d_in[12];
  const float* Wout = (const float*)d_in[13];
  const float* bout = (const float*)d_in[14];
  float* outp = (float*)d_out;

  float* ws   = (float*)d_ws;
  float* pout = ws;                                   // 3*33*16384 floats
  u16*   Bf   = (u16*)(ws + POUT_F);                  // 1.31 MB, 16B-aligned
  float* P    = (float*)(Bf + BF_U16);
  float* W2t  = P + PTAB_F;
  int*   side = (int*)(W2t + 64*64);                  // 16384*8 ints

  prep_bf<<<(2*NSLOT*128 + 255)/256, 256, 0, stream>>>(W_genre, W_dir, W_actor, Bf);
  prep_p<<<(PTAB_F + 255)/256, 256, 0, stream>>>(emb_rate, emb_gen, emb_age, emb_occ,
                                                 emb_area, W1, P);
  prep_w2t<<<16, 256, 0, stream>>>(W2, W2t);

  fusedK<<<NROW/32, 256, 0, stream>>>(x, Bf, pout, side);

  k2<<<NROW/64, 64, 0, stream>>>(side, pout, W_genre, W_actor, P, W1, b1, W2t,
                                 b2, Wout, bout, outp);
}